// Round 11
// baseline (392.253 us; speedup 1.0000x reference)
//
#include <hip/hip_runtime.h>
#include <math.h>

#define NN 20000      // nodes
#define NE 320000     // edges (without self loops)
#define NT 340000     // edges + self loops
#define NG 64         // graphs
#define HB 1329       // (NT+255)/256 hist/scatter blocks
#define CB 128        // W2->bf16 transpose blocks
#define AB 2          // a2p GEMV blocks
#define PREP_GRID (HB + CB + AB + NN / 4)

using short8  = __attribute__((ext_vector_type(8))) short;   // 8 x bf16 (4 VGPRs)
using float4v = __attribute__((ext_vector_type(4))) float;   // MFMA accumulator

__device__ __forceinline__ float lrelu(float v) { return v > 0.f ? v : 0.2f * v; }
__device__ __forceinline__ float elu1(float v)  { return v > 0.f ? v : (expf(v) - 1.f); }
__device__ __forceinline__ unsigned short f2bf(float f) {
    unsigned u = __float_as_uint(f);
    u += 0x7FFFu + ((u >> 16) & 1u);   // round to nearest even
    return (unsigned short)(u >> 16);
}
__device__ __forceinline__ float bf2f(unsigned short s) {
    return __uint_as_float(((unsigned)s) << 16);
}
__device__ __forceinline__ int ld_agent(const int* p) {
    return __hip_atomic_load(p, __ATOMIC_RELAXED, __HIP_MEMORY_SCOPE_AGENT);
}

__device__ __forceinline__ int esrc(const int* ei, int e) { return e < NE ? ei[e] : (e - NE); }
__device__ __forceinline__ int edst(const int* ei, int e) { return e < NE ? ei[NE + e] : (e - NE); }

// ---------- D1: fused prep ----------
// blocks [0,HB): grid-parallel dst histogram (global atomics); [HB,HB+CB): W2bfT;
// [HB+CB,+AB): a2p GEMV; rest: h1 transform + layer-1 logits.
// LAST block to finish (device counter) runs the exclusive scan -> rowstart/cursor/gstart.
__global__ void k_prep(const int* __restrict__ ei, const int* __restrict__ batch,
                       int* __restrict__ deg, int* __restrict__ done_ctr,
                       int* __restrict__ rowstart, int* __restrict__ cursor,
                       int* __restrict__ gstart,
                       const float* __restrict__ W2, unsigned short* __restrict__ W2bfT,
                       const float* __restrict__ as2, const float* __restrict__ ad2,
                       float* __restrict__ a2ps, float* __restrict__ a2pd,
                       const float* __restrict__ x, const float* __restrict__ W1,
                       const float* __restrict__ as1, const float* __restrict__ ad1,
                       unsigned short* __restrict__ h1bf, float* __restrict__ al_s,
                       float* __restrict__ al_d) {
    __shared__ int part[256];
    __shared__ float pp[4][64];
    __shared__ int s_last;
    int tid = threadIdx.x;
    int b = blockIdx.x;
    if (b < HB) {
        int t = b * 256 + tid;
        if (t < NE) atomicAdd(&deg[ei[NE + t]], 1);   // real edges only; self-loops added in scan
    } else if (b < HB + CB) {
        int t = (b - HB) * 256 + tid;  // t = n*64 + k
        int k = t & 63, n = t >> 6;
        W2bfT[t] = f2bf(W2[k * 512 + n]);
    } else if (b < HB + CB + AB) {
        // a2p[k] = sum_j W2[k][j] * a[j]   (64x512 GEMV)
        const float* av = (b == HB + CB) ? as2 : ad2;
        float* outp     = (b == HB + CB) ? a2ps : a2pd;
        int k = tid & 63, seg = tid >> 6;
        float s = 0.f;
        for (int j = seg * 128; j < seg * 128 + 128; ++j)
            s = fmaf(W2[k * 512 + j], av[j], s);
        pp[seg][k] = s;
        __syncthreads();
        if (tid < 64) outp[tid] = pp[0][tid] + pp[1][tid] + pp[2][tid] + pp[3][tid];
    } else {
        int n = (b - HB - CB - AB) * 4 + (tid >> 6);
        int j = tid & 63;
        float x0 = x[n * 3 + 0], x1 = x[n * 3 + 1], x2 = x[n * 3 + 2];
        float v = fmaf(x0, W1[j], fmaf(x1, W1[64 + j], x2 * W1[128 + j]));
        h1bf[n * 64 + j] = f2bf(v);
        float ps = v * as1[j];
        float pd = v * ad1[j];
        for (int o = 4; o >= 1; o >>= 1) {
            ps += __shfl_xor(ps, o, 8);
            pd += __shfl_xor(pd, o, 8);
        }
        if ((j & 7) == 0) {
            al_s[n * 8 + (j >> 3)] = ps;
            al_d[n * 8 + (j >> 3)] = pd;
        }
    }
    __syncthreads();
    if (tid == 0) {
        __threadfence();
        int old = atomicAdd(done_ctr, 1);
        s_last = (old == PREP_GRID - 1) ? 1 : 0;
    }
    __syncthreads();
    if (!s_last) return;
    // ---- tail: this block runs after every other block's work is globally visible ----
    __threadfence();
    int base = tid * 79;                       // 79*256 = 20224 >= NN
    int cnt = NN - base;
    cnt = cnt < 0 ? 0 : (cnt > 79 ? 79 : cnt);
    int s = 0;
    for (int i = 0; i < cnt; ++i) s += ld_agent(&deg[base + i]) + 1;   // +1 self-loop
    part[tid] = s;
    __syncthreads();
    for (int o = 1; o < 256; o <<= 1) {
        int v = (tid >= o) ? part[tid - o] : 0;
        __syncthreads();
        part[tid] += v;
        __syncthreads();
    }
    int run = (tid == 0) ? 0 : part[tid - 1];
    for (int i = 0; i < cnt; ++i) {
        int idx = base + i;
        rowstart[idx] = run;
        cursor[idx] = run;
        run += ld_agent(&deg[idx]) + 1;
    }
    if (tid == 0) rowstart[NN] = NT;
    if (tid <= NG) {  // gstart[t] = first node with batch >= t (batch sorted)
        int lo = 0, hi = NN;
        while (lo < hi) {
            int mid = (lo + hi) >> 1;
            if (batch[mid] < tid) lo = mid + 1; else hi = mid;
        }
        gstart[tid] = lo;
    }
}

// ---------- D2: CSR scatter ----------
__global__ void k_scatter(const int* __restrict__ ei, int* __restrict__ cursor,
                          int* __restrict__ csr_src) {
    int t = blockIdx.x * blockDim.x + threadIdx.x;
    if (t >= NT) return;
    int d = edst(ei, t), s = esrc(ei, t);
    int pos = atomicAdd(&cursor[d], 1);
    csr_src[pos] = s;
}

// ---------- D3: fused layer-1 softmax + aggregate + bias + elu -> o1bf; layer-2 logits ----------
__global__ void k_l1(const int* __restrict__ rowstart, const int* __restrict__ csr_src,
                     const float* __restrict__ al_s, const float* __restrict__ al_d,
                     const unsigned short* __restrict__ h1bf, const float* __restrict__ b1,
                     const float* __restrict__ a2ps, const float* __restrict__ a2pd,
                     unsigned short* __restrict__ o1bf, float* __restrict__ al_s2,
                     float* __restrict__ al_d2) {
    int n = blockIdx.x * 4 + (threadIdx.x >> 6);
    int j = threadIdx.x & 63;  // channel
    int h = j >> 3;            // head
    float ald = al_d[n * 8 + h];
    int start = rowstart[n], end = rowstart[n + 1];
    float m = -1e30f;
    for (int e = start + (j & 7); e < end; e += 8) {
        m = fmaxf(m, lrelu(al_s[csr_src[e] * 8 + h] + ald));
    }
    for (int o = 4; o >= 1; o >>= 1) m = fmaxf(m, __shfl_xor(m, o, 8));
    float denom = 0.f, acc = 0.f;
    int e = start;
    for (; e + 1 < end; e += 2) {
        int s0 = csr_src[e], s1 = csr_src[e + 1];
        float ex0 = __expf(lrelu(al_s[s0 * 8 + h] + ald) - m);
        float ex1 = __expf(lrelu(al_s[s1 * 8 + h] + ald) - m);
        denom += ex0 + ex1;
        acc = fmaf(ex0, bf2f(h1bf[s0 * 64 + j]), fmaf(ex1, bf2f(h1bf[s1 * 64 + j]), acc));
    }
    if (e < end) {
        int s0 = csr_src[e];
        float ex0 = __expf(lrelu(al_s[s0 * 8 + h] + ald) - m);
        denom += ex0;
        acc = fmaf(ex0, bf2f(h1bf[s0 * 64 + j]), acc);
    }
    float v = elu1(acc / denom + b1[j]);   // f32 o1 value
    o1bf[n * 64 + j] = f2bf(v);
    float ps = v * a2ps[j];
    float pd = v * a2pd[j];
    for (int o = 32; o >= 1; o >>= 1) {
        ps += __shfl_xor(ps, o, 64);
        pd += __shfl_xor(pd, o, 64);
    }
    if (j == 0) { al_s2[n] = ps; al_d2[n] = pd; }
}

// ---------- D4: fused layer-2 softmax-agg (64-dim) + MFMA @W2 + bias + elu + pool ----------
// 16 nodes/block, 512 threads (8 waves). Phase A: wave w aggregates nodes w*2,w*2+1 -> LDS bf16.
// Phase B: MFMA (A from LDS, B from W2bfT), elu, graph-masked pool -> atomics into sums.
__global__ void k_l2gemm(const int* __restrict__ rowstart, const int* __restrict__ csr_src,
                         const float* __restrict__ al_s2, const float* __restrict__ al_d2,
                         const unsigned short* __restrict__ o1bf,
                         const unsigned short* __restrict__ W2bfT,
                         const float* __restrict__ b2, const int* __restrict__ batch,
                         float* __restrict__ sums) {
    __shared__ unsigned short lagg[16][72];   // padded rows: 144B stride breaks bank aliasing
    int n0 = blockIdx.x * 16;
    int w = threadIdx.x >> 6, lane = threadIdx.x & 63;
#pragma unroll
    for (int i = 0; i < 2; ++i) {
        int r = w * 2 + i;
        int n = n0 + r;
        float ald = al_d2[n];
        int start = rowstart[n], end = rowstart[n + 1];
        float m = -1e30f;
        for (int e = start + lane; e < end; e += 64) {
            m = fmaxf(m, lrelu(al_s2[csr_src[e]] + ald));
        }
        for (int o = 32; o >= 1; o >>= 1) m = fmaxf(m, __shfl_xor(m, o, 64));
        float denom = 0.f, acc = 0.f;
        int e = start;
        for (; e + 1 < end; e += 2) {
            int s0 = csr_src[e], s1 = csr_src[e + 1];
            float ex0 = __expf(lrelu(al_s2[s0] + ald) - m);
            float ex1 = __expf(lrelu(al_s2[s1] + ald) - m);
            denom += ex0 + ex1;
            acc = fmaf(ex0, bf2f(o1bf[s0 * 64 + lane]),
                       fmaf(ex1, bf2f(o1bf[s1 * 64 + lane]), acc));
        }
        if (e < end) {
            int s0 = csr_src[e];
            float ex0 = __expf(lrelu(al_s2[s0] + ald) - m);
            denom += ex0;
            acc = fmaf(ex0, bf2f(o1bf[s0 * 64 + lane]), acc);
        }
        lagg[r][lane] = f2bf(acc / denom);
    }
    __syncthreads();
    // phase B: A[m=lane&15][k=quad*8+j] from LDS; B[k][n=lane&15] from W2bfT (n-major).
    int mcol = lane & 15;
    int q = lane >> 4;
    short8 a0 = *(const short8*)&lagg[mcol][q * 8];
    short8 a1 = *(const short8*)&lagg[mcol][32 + q * 8];
    int gmin = batch[n0], gmax = batch[n0 + 15];
    int batchq[4];
#pragma unroll
    for (int r = 0; r < 4; ++r) batchq[r] = batch[n0 + q * 4 + r];
#pragma unroll
    for (int t = 0; t < 4; ++t) {
        int c = w * 64 + t * 16 + mcol;
        const unsigned short* bp = W2bfT + c * 64 + q * 8;
        short8 b0 = *(const short8*)bp;
        short8 b1 = *(const short8*)(bp + 32);
        float4v acc = {0.f, 0.f, 0.f, 0.f};
        acc = __builtin_amdgcn_mfma_f32_16x16x32_bf16(a0, b0, acc, 0, 0, 0);
        acc = __builtin_amdgcn_mfma_f32_16x16x32_bf16(a1, b1, acc, 0, 0, 0);
        float bias = b2[c];
        float val[4];
#pragma unroll
        for (int r = 0; r < 4; ++r) val[r] = elu1(acc[r] + bias);
        for (int g = gmin; g <= gmax; ++g) {
            float s = 0.f;
#pragma unroll
            for (int r = 0; r < 4; ++r) s += (batchq[r] == g) ? val[r] : 0.f;
            s += __shfl_xor(s, 16, 64);   // reduce across the 4 quads
            s += __shfl_xor(s, 32, 64);
            if (q == 0) atomicAdd(&sums[g * 512 + c], s);
        }
    }
}

// ---------- D5: final GEMM: out[g][j] = (sums[g] @ Wo[:,j]) / cnt[g] + bo[j] ----------
__global__ void k_final(const float* __restrict__ sums, const int* __restrict__ gstart,
                        const float* __restrict__ Wo, const float* __restrict__ bo,
                        float* __restrict__ out) {
    __shared__ float sp[512];
    int g = blockIdx.x >> 3;
    int j = (blockIdx.x & 7) * 64 + threadIdx.x;  // 64 threads
    for (int k = threadIdx.x; k < 512; k += 64) sp[k] = sums[g * 512 + k];
    __syncthreads();
    float c = (float)(gstart[g + 1] - gstart[g]);
    float inv = 1.f / (c > 0.f ? c : 1.f);
    float acc = 0.f;
    for (int k = 0; k < 512; ++k) acc = fmaf(sp[k], Wo[k * 512 + j], acc);
    out[g * 512 + j] = fmaf(acc, inv, bo[j]);
}

extern "C" void kernel_launch(void* const* d_in, const int* in_sizes, int n_in,
                              void* d_out, int out_size, void* d_ws, size_t ws_size,
                              hipStream_t stream) {
    const float* x     = (const float*)d_in[0];
    const int*   ei    = (const int*)d_in[1];    // [2, NE]
    const int*   batch = (const int*)d_in[2];    // [NN] sorted
    const float* W1    = (const float*)d_in[3];
    const float* as1   = (const float*)d_in[4];
    const float* ad1   = (const float*)d_in[5];
    const float* b1    = (const float*)d_in[6];
    const float* W2    = (const float*)d_in[7];
    const float* as2   = (const float*)d_in[8];
    const float* ad2   = (const float*)d_in[9];
    const float* b2    = (const float*)d_in[10];
    const float* Wo    = (const float*)d_in[11];
    const float* bo    = (const float*)d_in[12];
    float* out = (float*)d_out;

    // ---- workspace arena (4-byte units) ----
    float* w = (float*)d_ws;
    unsigned short* h1bf  = (unsigned short*)(w + 0);        // 640,000 units
    float* al_s1 = w + 640000;     // 160,000
    float* al_d1 = w + 800000;     // 160,000
    unsigned short* o1bf  = (unsigned short*)(w + 960000);   // 640,000 units (byte 3,840,000: 16B aligned)
    unsigned short* W2bfT = (unsigned short*)(w + 1600000);  // 16,384 units (byte 6,400,000: 16B aligned)
    float* a2ps  = w + 1616384;    // 64
    float* a2pd  = w + 1616448;    // 64
    float* al_s2 = w + 1616512;    // 20,000
    float* al_d2 = w + 1636512;    // 20,000
    int*   rowstart = (int*)(w + 1656512);   // 20,001
    int*   cursor   = (int*)(w + 1676516);   // 20,000
    int*   csr_src  = (int*)(w + 1696516);   // 340,000
    int*   gstart   = (int*)(w + 2036516);   // 65
    // ---- zero-initialized region (one contiguous memset) ----
    int*   deg      = (int*)(w + 2036584);   // 20,000
    float* sums     = w + 2056584;           // 32,768
    int*   done_ctr = (int*)(w + 2089352);   // 4 (padded)
    // end: 2,089,356 units ≈ 8.4 MB

    hipMemsetAsync(w + 2036584, 0, (size_t)(20000 + 32768 + 4) * 4, stream);

    k_prep   <<<PREP_GRID, 256, 0, stream>>>(ei, batch, deg, done_ctr, rowstart, cursor,
                                             gstart, W2, W2bfT, as2, ad2, a2ps, a2pd,
                                             x, W1, as1, ad1, h1bf, al_s1, al_d1);
    k_scatter<<<HB, 256, 0, stream>>>(ei, cursor, csr_src);
    k_l1     <<<NN / 4, 256, 0, stream>>>(rowstart, csr_src, al_s1, al_d1, h1bf, b1,
                                          a2ps, a2pd, o1bf, al_s2, al_d2);
    k_l2gemm <<<NN / 16, 512, 0, stream>>>(rowstart, csr_src, al_s2, al_d2, o1bf,
                                           W2bfT, b2, batch, sums);
    k_final  <<<NG * 8, 64, 0, stream>>>(sums, gstart, Wo, bo, out);
}

// Round 12
// 223.723 us; speedup vs baseline: 1.7533x; 1.7533x over previous
//
#include <hip/hip_runtime.h>
#include <math.h>

#define NN 20000      // nodes
#define NE 320000     // edges (without self loops)
#define NT 340000     // edges + self loops
#define NG 64         // graphs
#define HB 1329       // (NT+255)/256 hist/scatter blocks
#define CB 128        // W2->bf16 transpose blocks
#define AB 2          // a2p GEMV blocks

using short8  = __attribute__((ext_vector_type(8))) short;   // 8 x bf16 (4 VGPRs)
using float4v = __attribute__((ext_vector_type(4))) float;   // MFMA accumulator

__device__ __forceinline__ float lrelu(float v) { return v > 0.f ? v : 0.2f * v; }
__device__ __forceinline__ float elu1(float v)  { return v > 0.f ? v : (expf(v) - 1.f); }
__device__ __forceinline__ unsigned short f2bf(float f) {
    unsigned u = __float_as_uint(f);
    u += 0x7FFFu + ((u >> 16) & 1u);   // round to nearest even
    return (unsigned short)(u >> 16);
}
__device__ __forceinline__ float bf2f(unsigned short s) {
    return __uint_as_float(((unsigned)s) << 16);
}

__device__ __forceinline__ int esrc(const int* ei, int e) { return e < NE ? ei[e] : (e - NE); }
__device__ __forceinline__ int edst(const int* ei, int e) { return e < NE ? ei[NE + e] : (e - NE); }

// ---------- D1: fused prep (all grid-parallel; no serial tail) ----------
// blocks [0,HB): dst histogram (global atomics, real edges only — self-loops added in scan);
// [HB,HB+CB): W2 transpose->bf16; [HB+CB,+AB): a2p GEMV; rest: h1 transform + layer-1 logits.
__global__ void k_prep(const int* __restrict__ ei, int* __restrict__ deg,
                       const float* __restrict__ W2, unsigned short* __restrict__ W2bfT,
                       const float* __restrict__ as2, const float* __restrict__ ad2,
                       float* __restrict__ a2ps, float* __restrict__ a2pd,
                       const float* __restrict__ x, const float* __restrict__ W1,
                       const float* __restrict__ as1, const float* __restrict__ ad1,
                       unsigned short* __restrict__ h1bf, float* __restrict__ al_s,
                       float* __restrict__ al_d) {
    int tid = threadIdx.x;
    int b = blockIdx.x;
    if (b < HB) {
        int t = b * 256 + tid;
        if (t < NE) atomicAdd(&deg[ei[NE + t]], 1);
        return;
    }
    if (b < HB + CB) {
        int t = (b - HB) * 256 + tid;  // t = n*64 + k
        int k = t & 63, n = t >> 6;
        W2bfT[t] = f2bf(W2[k * 512 + n]);
        return;
    }
    if (b < HB + CB + AB) {
        // a2p[k] = sum_j W2[k][j] * a[j]   (64x512 GEMV)
        __shared__ float pp[4][64];
        const float* av = (b == HB + CB) ? as2 : ad2;
        float* outp     = (b == HB + CB) ? a2ps : a2pd;
        int k = tid & 63, seg = tid >> 6;
        float s = 0.f;
        for (int j = seg * 128; j < seg * 128 + 128; ++j)
            s = fmaf(W2[k * 512 + j], av[j], s);
        pp[seg][k] = s;
        __syncthreads();
        if (tid < 64) outp[tid] = pp[0][tid] + pp[1][tid] + pp[2][tid] + pp[3][tid];
        return;
    }
    int n = (b - HB - CB - AB) * 4 + (tid >> 6);
    int j = tid & 63;
    float x0 = x[n * 3 + 0], x1 = x[n * 3 + 1], x2 = x[n * 3 + 2];
    float v = fmaf(x0, W1[j], fmaf(x1, W1[64 + j], x2 * W1[128 + j]));
    h1bf[n * 64 + j] = f2bf(v);
    float ps = v * as1[j];
    float pd = v * ad1[j];
    for (int o = 4; o >= 1; o >>= 1) {
        ps += __shfl_xor(ps, o, 8);
        pd += __shfl_xor(pd, o, 8);
    }
    if ((j & 7) == 0) {
        al_s[n * 8 + (j >> 3)] = ps;
        al_d[n * 8 + (j >> 3)] = pd;
    }
}

// ---------- D2: single-block scan (plain cached loads, L2-hot) ----------
// exclusive scan of (deg+1) -> rowstart/cursor; binary-search gstart from sorted batch
__global__ void k_scan(const int* __restrict__ deg, const int* __restrict__ batch,
                       int* __restrict__ rowstart, int* __restrict__ cursor,
                       int* __restrict__ gstart) {
    __shared__ int part[1024];
    int t = threadIdx.x;
    int base = t * 20;
    int local[20];
    int s = 0;
    if (base < NN) {
#pragma unroll
        for (int i = 0; i < 20; ++i) { local[i] = deg[base + i] + 1; s += local[i]; }
    }
    part[t] = s;
    __syncthreads();
    for (int o = 1; o < 1024; o <<= 1) {
        int v = (t >= o) ? part[t - o] : 0;
        __syncthreads();
        part[t] += v;
        __syncthreads();
    }
    if (base < NN) {
        int run = (t == 0) ? 0 : part[t - 1];
#pragma unroll
        for (int i = 0; i < 20; ++i) {
            rowstart[base + i] = run;
            cursor[base + i] = run;
            run += local[i];
        }
    }
    if (t == 1023) rowstart[NN] = NT;
    if (t <= NG) {  // gstart[t] = first node with batch >= t (batch sorted)
        int lo = 0, hi = NN;
        while (lo < hi) {
            int mid = (lo + hi) >> 1;
            if (batch[mid] < t) lo = mid + 1; else hi = mid;
        }
        gstart[t] = lo;
    }
}

// ---------- D3: CSR scatter ----------
__global__ void k_scatter(const int* __restrict__ ei, int* __restrict__ cursor,
                          int* __restrict__ csr_src) {
    int t = blockIdx.x * blockDim.x + threadIdx.x;
    if (t >= NT) return;
    int d = edst(ei, t), s = esrc(ei, t);
    int pos = atomicAdd(&cursor[d], 1);
    csr_src[pos] = s;
}

// ---------- D4: fused layer-1 softmax + aggregate + bias + elu -> o1bf; layer-2 logits ----------
__global__ void k_l1(const int* __restrict__ rowstart, const int* __restrict__ csr_src,
                     const float* __restrict__ al_s, const float* __restrict__ al_d,
                     const unsigned short* __restrict__ h1bf, const float* __restrict__ b1,
                     const float* __restrict__ a2ps, const float* __restrict__ a2pd,
                     unsigned short* __restrict__ o1bf, float* __restrict__ al_s2,
                     float* __restrict__ al_d2) {
    int n = blockIdx.x * 4 + (threadIdx.x >> 6);
    int j = threadIdx.x & 63;  // channel
    int h = j >> 3;            // head
    float ald = al_d[n * 8 + h];
    int start = rowstart[n], end = rowstart[n + 1];
    float m = -1e30f;
    for (int e = start + (j & 7); e < end; e += 8) {
        m = fmaxf(m, lrelu(al_s[csr_src[e] * 8 + h] + ald));
    }
    for (int o = 4; o >= 1; o >>= 1) m = fmaxf(m, __shfl_xor(m, o, 8));
    float denom = 0.f, acc = 0.f;
    int e = start;
    for (; e + 1 < end; e += 2) {
        int s0 = csr_src[e], s1 = csr_src[e + 1];
        float ex0 = __expf(lrelu(al_s[s0 * 8 + h] + ald) - m);
        float ex1 = __expf(lrelu(al_s[s1 * 8 + h] + ald) - m);
        denom += ex0 + ex1;
        acc = fmaf(ex0, bf2f(h1bf[s0 * 64 + j]), fmaf(ex1, bf2f(h1bf[s1 * 64 + j]), acc));
    }
    if (e < end) {
        int s0 = csr_src[e];
        float ex0 = __expf(lrelu(al_s[s0 * 8 + h] + ald) - m);
        denom += ex0;
        acc = fmaf(ex0, bf2f(h1bf[s0 * 64 + j]), acc);
    }
    float v = elu1(acc / denom + b1[j]);   // f32 o1 value
    o1bf[n * 64 + j] = f2bf(v);
    float ps = v * a2ps[j];
    float pd = v * a2pd[j];
    for (int o = 32; o >= 1; o >>= 1) {
        ps += __shfl_xor(ps, o, 64);
        pd += __shfl_xor(pd, o, 64);
    }
    if (j == 0) { al_s2[n] = ps; al_d2[n] = pd; }
}

// ---------- D5: fused layer-2 softmax-agg (64-dim) + MFMA @W2 + bias + elu + pool ----------
// 16 nodes/block, 512 threads (8 waves). Phase A: wave w aggregates nodes w*2,w*2+1 -> LDS bf16.
// Phase B: MFMA (A from LDS, B from W2bfT), elu, graph-masked pool -> atomics into sums.
__global__ void k_l2gemm(const int* __restrict__ rowstart, const int* __restrict__ csr_src,
                         const float* __restrict__ al_s2, const float* __restrict__ al_d2,
                         const unsigned short* __restrict__ o1bf,
                         const unsigned short* __restrict__ W2bfT,
                         const float* __restrict__ b2, const int* __restrict__ batch,
                         float* __restrict__ sums) {
    __shared__ unsigned short lagg[16][72];   // padded rows: 144B stride breaks bank aliasing
    int n0 = blockIdx.x * 16;
    int w = threadIdx.x >> 6, lane = threadIdx.x & 63;
#pragma unroll
    for (int i = 0; i < 2; ++i) {
        int r = w * 2 + i;
        int n = n0 + r;
        float ald = al_d2[n];
        int start = rowstart[n], end = rowstart[n + 1];
        float m = -1e30f;
        for (int e = start + lane; e < end; e += 64) {
            m = fmaxf(m, lrelu(al_s2[csr_src[e]] + ald));
        }
        for (int o = 32; o >= 1; o >>= 1) m = fmaxf(m, __shfl_xor(m, o, 64));
        float denom = 0.f, acc = 0.f;
        int e = start;
        for (; e + 1 < end; e += 2) {
            int s0 = csr_src[e], s1 = csr_src[e + 1];
            float ex0 = __expf(lrelu(al_s2[s0] + ald) - m);
            float ex1 = __expf(lrelu(al_s2[s1] + ald) - m);
            denom += ex0 + ex1;
            acc = fmaf(ex0, bf2f(o1bf[s0 * 64 + lane]),
                       fmaf(ex1, bf2f(o1bf[s1 * 64 + lane]), acc));
        }
        if (e < end) {
            int s0 = csr_src[e];
            float ex0 = __expf(lrelu(al_s2[s0] + ald) - m);
            denom += ex0;
            acc = fmaf(ex0, bf2f(o1bf[s0 * 64 + lane]), acc);
        }
        lagg[r][lane] = f2bf(acc / denom);
    }
    __syncthreads();
    // phase B: A[m=lane&15][k=quad*8+j] from LDS; B[k][n=lane&15] from W2bfT (n-major).
    int mcol = lane & 15;
    int q = lane >> 4;
    short8 a0 = *(const short8*)&lagg[mcol][q * 8];
    short8 a1 = *(const short8*)&lagg[mcol][32 + q * 8];
    int gmin = batch[n0], gmax = batch[n0 + 15];
    int batchq[4];
#pragma unroll
    for (int r = 0; r < 4; ++r) batchq[r] = batch[n0 + q * 4 + r];
#pragma unroll
    for (int t = 0; t < 4; ++t) {
        int c = w * 64 + t * 16 + mcol;
        const unsigned short* bp = W2bfT + c * 64 + q * 8;
        short8 b0 = *(const short8*)bp;
        short8 b1 = *(const short8*)(bp + 32);
        float4v acc = {0.f, 0.f, 0.f, 0.f};
        acc = __builtin_amdgcn_mfma_f32_16x16x32_bf16(a0, b0, acc, 0, 0, 0);
        acc = __builtin_amdgcn_mfma_f32_16x16x32_bf16(a1, b1, acc, 0, 0, 0);
        float bias = b2[c];
        float val[4];
#pragma unroll
        for (int r = 0; r < 4; ++r) val[r] = elu1(acc[r] + bias);
        for (int g = gmin; g <= gmax; ++g) {
            float s = 0.f;
#pragma unroll
            for (int r = 0; r < 4; ++r) s += (batchq[r] == g) ? val[r] : 0.f;
            s += __shfl_xor(s, 16, 64);   // reduce across the 4 quads
            s += __shfl_xor(s, 32, 64);
            if (q == 0) atomicAdd(&sums[g * 512 + c], s);
        }
    }
}

// ---------- D6: final GEMM: out[g][j] = (sums[g] @ Wo[:,j]) / cnt[g] + bo[j] ----------
__global__ void k_final(const float* __restrict__ sums, const int* __restrict__ gstart,
                        const float* __restrict__ Wo, const float* __restrict__ bo,
                        float* __restrict__ out) {
    __shared__ float sp[512];
    int g = blockIdx.x >> 3;
    int j = (blockIdx.x & 7) * 64 + threadIdx.x;  // 64 threads
    for (int k = threadIdx.x; k < 512; k += 64) sp[k] = sums[g * 512 + k];
    __syncthreads();
    float c = (float)(gstart[g + 1] - gstart[g]);
    float inv = 1.f / (c > 0.f ? c : 1.f);
    float acc = 0.f;
    for (int k = 0; k < 512; ++k) acc = fmaf(sp[k], Wo[k * 512 + j], acc);
    out[g * 512 + j] = fmaf(acc, inv, bo[j]);
}

extern "C" void kernel_launch(void* const* d_in, const int* in_sizes, int n_in,
                              void* d_out, int out_size, void* d_ws, size_t ws_size,
                              hipStream_t stream) {
    const float* x     = (const float*)d_in[0];
    const int*   ei    = (const int*)d_in[1];    // [2, NE]
    const int*   batch = (const int*)d_in[2];    // [NN] sorted
    const float* W1    = (const float*)d_in[3];
    const float* as1   = (const float*)d_in[4];
    const float* ad1   = (const float*)d_in[5];
    const float* b1    = (const float*)d_in[6];
    const float* W2    = (const float*)d_in[7];
    const float* as2   = (const float*)d_in[8];
    const float* ad2   = (const float*)d_in[9];
    const float* b2    = (const float*)d_in[10];
    const float* Wo    = (const float*)d_in[11];
    const float* bo    = (const float*)d_in[12];
    float* out = (float*)d_out;

    // ---- workspace arena (4-byte units) ----
    float* w = (float*)d_ws;
    unsigned short* h1bf  = (unsigned short*)(w + 0);        // 640,000 units
    float* al_s1 = w + 640000;     // 160,000
    float* al_d1 = w + 800000;     // 160,000
    unsigned short* o1bf  = (unsigned short*)(w + 960000);   // 640,000 units (byte 3,840,000: 16B aligned)
    unsigned short* W2bfT = (unsigned short*)(w + 1600000);  // 16,384 units (byte 6,400,000: 16B aligned)
    float* a2ps  = w + 1616384;    // 64
    float* a2pd  = w + 1616448;    // 64
    float* al_s2 = w + 1616512;    // 20,000
    float* al_d2 = w + 1636512;    // 20,000
    int*   rowstart = (int*)(w + 1656512);   // 20,001
    int*   cursor   = (int*)(w + 1676516);   // 20,000
    int*   csr_src  = (int*)(w + 1696516);   // 340,000
    int*   gstart   = (int*)(w + 2036516);   // 65
    // ---- zero-initialized region (one contiguous memset) ----
    int*   deg      = (int*)(w + 2036584);   // 20,000
    float* sums     = w + 2056584;           // 32,768
    // end: 2,089,352 units ≈ 8.4 MB

    hipMemsetAsync(w + 2036584, 0, (size_t)(20000 + 32768) * 4, stream);

    k_prep   <<<HB + CB + AB + NN / 4, 256, 0, stream>>>(ei, deg, W2, W2bfT, as2, ad2,
                                                         a2ps, a2pd, x, W1, as1, ad1,
                                                         h1bf, al_s1, al_d1);
    k_scan   <<<1, 1024, 0, stream>>>(deg, batch, rowstart, cursor, gstart);
    k_scatter<<<HB, 256, 0, stream>>>(ei, cursor, csr_src);
    k_l1     <<<NN / 4, 256, 0, stream>>>(rowstart, csr_src, al_s1, al_d1, h1bf, b1,
                                          a2ps, a2pd, o1bf, al_s2, al_d2);
    k_l2gemm <<<NN / 16, 512, 0, stream>>>(rowstart, csr_src, al_s2, al_d2, o1bf,
                                           W2bfT, b2, batch, sums);
    k_final  <<<NG * 8, 64, 0, stream>>>(sums, gstart, Wo, bo, out);
}

// Round 13
// 209.245 us; speedup vs baseline: 1.8746x; 1.0692x over previous
//
#include <hip/hip_runtime.h>
#include <math.h>

#define NN 20000      // nodes
#define NE 320000     // edges (without self loops)
#define NT 340000     // edges + self loops
#define NG 64         // graphs
#define HB 1329       // (NT+255)/256 hist/scatter blocks
#define CB 128        // W2->bf16 transpose blocks
#define AB 2          // a2p GEMV blocks

using short8  = __attribute__((ext_vector_type(8))) short;   // 8 x bf16 (4 VGPRs)
using float4v = __attribute__((ext_vector_type(4))) float;   // MFMA accumulator

__device__ __forceinline__ float lrelu(float v) { return v > 0.f ? v : 0.2f * v; }
__device__ __forceinline__ float elu1(float v)  { return v > 0.f ? v : (expf(v) - 1.f); }
__device__ __forceinline__ unsigned short f2bf(float f) {
    unsigned u = __float_as_uint(f);
    u += 0x7FFFu + ((u >> 16) & 1u);   // round to nearest even
    return (unsigned short)(u >> 16);
}
__device__ __forceinline__ float bf2f(unsigned short s) {
    return __uint_as_float(((unsigned)s) << 16);
}

__device__ __forceinline__ int esrc(const int* ei, int e) { return e < NE ? ei[e] : (e - NE); }
__device__ __forceinline__ int edst(const int* ei, int e) { return e < NE ? ei[NE + e] : (e - NE); }

// ---------- D1: fused prep (all grid-parallel; no serial tail) ----------
__global__ void k_prep(const int* __restrict__ ei, int* __restrict__ deg,
                       const float* __restrict__ W2, unsigned short* __restrict__ W2bfT,
                       const float* __restrict__ as2, const float* __restrict__ ad2,
                       float* __restrict__ a2ps, float* __restrict__ a2pd,
                       const float* __restrict__ x, const float* __restrict__ W1,
                       const float* __restrict__ as1, const float* __restrict__ ad1,
                       unsigned short* __restrict__ h1bf, float* __restrict__ al_s,
                       float* __restrict__ al_d) {
    int tid = threadIdx.x;
    int b = blockIdx.x;
    if (b < HB) {
        int t = b * 256 + tid;
        if (t < NE) atomicAdd(&deg[ei[NE + t]], 1);
        return;
    }
    if (b < HB + CB) {
        int t = (b - HB) * 256 + tid;  // t = n*64 + k
        int k = t & 63, n = t >> 6;
        W2bfT[t] = f2bf(W2[k * 512 + n]);
        return;
    }
    if (b < HB + CB + AB) {
        // a2p[k] = sum_j W2[k][j] * a[j]   (64x512 GEMV)
        __shared__ float pp[4][64];
        const float* av = (b == HB + CB) ? as2 : ad2;
        float* outp     = (b == HB + CB) ? a2ps : a2pd;
        int k = tid & 63, seg = tid >> 6;
        float s = 0.f;
        for (int j = seg * 128; j < seg * 128 + 128; ++j)
            s = fmaf(W2[k * 512 + j], av[j], s);
        pp[seg][k] = s;
        __syncthreads();
        if (tid < 64) outp[tid] = pp[0][tid] + pp[1][tid] + pp[2][tid] + pp[3][tid];
        return;
    }
    int n = (b - HB - CB - AB) * 4 + (tid >> 6);
    int j = tid & 63;
    float x0 = x[n * 3 + 0], x1 = x[n * 3 + 1], x2 = x[n * 3 + 2];
    float v = fmaf(x0, W1[j], fmaf(x1, W1[64 + j], x2 * W1[128 + j]));
    h1bf[n * 64 + j] = f2bf(v);
    float ps = v * as1[j];
    float pd = v * ad1[j];
    for (int o = 4; o >= 1; o >>= 1) {
        ps += __shfl_xor(ps, o, 8);
        pd += __shfl_xor(pd, o, 8);
    }
    if ((j & 7) == 0) {
        al_s[n * 8 + (j >> 3)] = ps;
        al_d[n * 8 + (j >> 3)] = pd;
    }
}

// ---------- D2: single-block scan (plain cached loads, L2-hot) ----------
__global__ void k_scan(const int* __restrict__ deg, const int* __restrict__ batch,
                       int* __restrict__ rowstart, int* __restrict__ cursor,
                       int* __restrict__ gstart) {
    __shared__ int part[1024];
    int t = threadIdx.x;
    int base = t * 20;
    int local[20];
    int s = 0;
    if (base < NN) {
#pragma unroll
        for (int i = 0; i < 20; ++i) { local[i] = deg[base + i] + 1; s += local[i]; }
    }
    part[t] = s;
    __syncthreads();
    for (int o = 1; o < 1024; o <<= 1) {
        int v = (t >= o) ? part[t - o] : 0;
        __syncthreads();
        part[t] += v;
        __syncthreads();
    }
    if (base < NN) {
        int run = (t == 0) ? 0 : part[t - 1];
#pragma unroll
        for (int i = 0; i < 20; ++i) {
            rowstart[base + i] = run;
            cursor[base + i] = run;
            run += local[i];
        }
    }
    if (t == 1023) rowstart[NN] = NT;
    if (t <= NG) {
        int lo = 0, hi = NN;
        while (lo < hi) {
            int mid = (lo + hi) >> 1;
            if (batch[mid] < t) lo = mid + 1; else hi = mid;
        }
        gstart[t] = lo;
    }
}

// ---------- D3: CSR scatter ----------
__global__ void k_scatter(const int* __restrict__ ei, int* __restrict__ cursor,
                          int* __restrict__ csr_src) {
    int t = blockIdx.x * blockDim.x + threadIdx.x;
    if (t >= NT) return;
    int d = edst(ei, t), s = esrc(ei, t);
    int pos = atomicAdd(&cursor[d], 1);
    csr_src[pos] = s;
}

// ---------- D4: fused layer-1 softmax + aggregate + bias + elu -> o1bf; layer-2 logits ----------
// 4 nodes/block (1 wave each). Softmax precomputed lane-parallel into LDS; gather loop 4-unrolled.
__global__ void k_l1(const int* __restrict__ rowstart, const int* __restrict__ csr_src,
                     const float* __restrict__ al_s, const float* __restrict__ al_d,
                     const unsigned short* __restrict__ h1bf, const float* __restrict__ b1,
                     const float* __restrict__ a2ps, const float* __restrict__ a2pd,
                     unsigned short* __restrict__ o1bf, float* __restrict__ al_s2,
                     float* __restrict__ al_d2) {
    __shared__ float lex1[4][8][66];   // [node][head][edge-slot], padded to 66 (bank spread)
    int nb = threadIdx.x >> 6;
    int n = blockIdx.x * 4 + nb;
    int j = threadIdx.x & 63;  // channel
    int h = j >> 3, sub = j & 7;
    float ald = al_d[n * 8 + h];
    int start = rowstart[n], end = rowstart[n + 1];
    int deg = end - start;
    // pass 1 (8-lane parallel per head): logits + max
    float m = -1e30f, lg0 = -1e30f;
    {
        int idx = 0;
        for (int e = start + sub; e < end; e += 8, ++idx) {
            float lg = lrelu(al_s[csr_src[e] * 8 + h] + ald);
            if (idx == 0) lg0 = lg;
            m = fmaxf(m, lg);
        }
    }
    for (int o = 4; o >= 1; o >>= 1) m = fmaxf(m, __shfl_xor(m, o, 8));
    // pass 2: ex + denom (shuffle-reduced); cache first 64 edges' ex in LDS
    float dsum = 0.f;
    {
        int idx = 0;
        for (int e = start + sub; e < end; e += 8, ++idx) {
            float lg = (idx == 0) ? lg0 : lrelu(al_s[csr_src[e] * 8 + h] + ald);
            float ex = __expf(lg - m);
            dsum += ex;
            if (idx < 8) lex1[nb][h][sub + idx * 8] = ex;
        }
    }
    for (int o = 4; o >= 1; o >>= 1) dsum += __shfl_xor(dsum, o, 8);
    // aggregate: LDS ex (broadcast per head) + h1bf gather, 4-unrolled
    int cap = deg < 64 ? deg : 64;
    float acc = 0.f;
    int i = 0;
    for (; i + 3 < cap; i += 4) {
        int s0 = csr_src[start + i], s1 = csr_src[start + i + 1];
        int s2 = csr_src[start + i + 2], s3 = csr_src[start + i + 3];
        float e0 = lex1[nb][h][i], e1 = lex1[nb][h][i + 1];
        float e2 = lex1[nb][h][i + 2], e3 = lex1[nb][h][i + 3];
        acc = fmaf(e0, bf2f(h1bf[s0 * 64 + j]), acc);
        acc = fmaf(e1, bf2f(h1bf[s1 * 64 + j]), acc);
        acc = fmaf(e2, bf2f(h1bf[s2 * 64 + j]), acc);
        acc = fmaf(e3, bf2f(h1bf[s3 * 64 + j]), acc);
    }
    for (; i < cap; ++i) {
        acc = fmaf(lex1[nb][h][i], bf2f(h1bf[csr_src[start + i] * 64 + j]), acc);
    }
    for (int e = start + 64; e < end; ++e) {   // overflow path (deg > 64), effectively never
        float ex = __expf(lrelu(al_s[csr_src[e] * 8 + h] + ald) - m);
        acc = fmaf(ex, bf2f(h1bf[csr_src[e] * 64 + j]), acc);
    }
    float v = elu1(acc / dsum + b1[j]);   // f32 o1 value
    o1bf[n * 64 + j] = f2bf(v);
    float ps = v * a2ps[j];
    float pd = v * a2pd[j];
    for (int o = 32; o >= 1; o >>= 1) {
        ps += __shfl_xor(ps, o, 64);
        pd += __shfl_xor(pd, o, 64);
    }
    if (j == 0) { al_s2[n] = ps; al_d2[n] = pd; }
}

// ---------- D5: fused layer-2 softmax-agg (64-dim) + MFMA @W2 + bias + elu + pool ----------
// 16 nodes/block, 512 threads (8 waves). Phase A: wave w handles nodes w*2,w*2+1; softmax
// precomputed lane-parallel (max+denom via shuffle), ex cached in LDS (broadcast reads free),
// gather loop 4-unrolled. Phase B: MFMA + elu + graph-masked pool -> atomics into sums.
__global__ void k_l2gemm(const int* __restrict__ rowstart, const int* __restrict__ csr_src,
                         const float* __restrict__ al_s2, const float* __restrict__ al_d2,
                         const unsigned short* __restrict__ o1bf,
                         const unsigned short* __restrict__ W2bfT,
                         const float* __restrict__ b2, const int* __restrict__ batch,
                         float* __restrict__ sums) {
    __shared__ unsigned short lagg[16][72];   // padded rows: 144B stride breaks bank aliasing
    __shared__ float lex[16][64];             // per-node cached edge exps (intra-wave use only)
    int n0 = blockIdx.x * 16;
    int w = threadIdx.x >> 6, lane = threadIdx.x & 63;
#pragma unroll
    for (int i = 0; i < 2; ++i) {
        int r = w * 2 + i;
        int n = n0 + r;
        float ald = al_d2[n];
        int start = rowstart[n], end = rowstart[n + 1];
        int deg = end - start;
        // pass 1 (lane-parallel): logits + max
        float m = -1e30f, lg0 = -1e30f;
        {
            int idx = 0;
            for (int e = start + lane; e < end; e += 64, ++idx) {
                float lg = lrelu(al_s2[csr_src[e]] + ald);
                if (idx == 0) lg0 = lg;
                m = fmaxf(m, lg);
            }
        }
        for (int o = 32; o >= 1; o >>= 1) m = fmaxf(m, __shfl_xor(m, o, 64));
        // pass 2: ex + denom via shuffle; cache first 64 in LDS
        float dsum = 0.f;
        {
            int idx = 0;
            for (int e = start + lane; e < end; e += 64, ++idx) {
                float lg = (idx == 0) ? lg0 : lrelu(al_s2[csr_src[e]] + ald);
                float ex = __expf(lg - m);
                dsum += ex;
                if (idx == 0) lex[r][lane] = ex;
            }
        }
        for (int o = 32; o >= 1; o >>= 1) dsum += __shfl_xor(dsum, o, 64);
        // aggregate: LDS ex broadcast + o1bf gather, 4-unrolled
        int cap = deg < 64 ? deg : 64;
        float acc = 0.f;
        int i2 = 0;
        for (; i2 + 3 < cap; i2 += 4) {
            int s0 = csr_src[start + i2], s1 = csr_src[start + i2 + 1];
            int s2 = csr_src[start + i2 + 2], s3 = csr_src[start + i2 + 3];
            float e0 = lex[r][i2], e1 = lex[r][i2 + 1];
            float e2 = lex[r][i2 + 2], e3 = lex[r][i2 + 3];
            acc = fmaf(e0, bf2f(o1bf[s0 * 64 + lane]), acc);
            acc = fmaf(e1, bf2f(o1bf[s1 * 64 + lane]), acc);
            acc = fmaf(e2, bf2f(o1bf[s2 * 64 + lane]), acc);
            acc = fmaf(e3, bf2f(o1bf[s3 * 64 + lane]), acc);
        }
        for (; i2 < cap; ++i2) {
            acc = fmaf(lex[r][i2], bf2f(o1bf[csr_src[start + i2] * 64 + lane]), acc);
        }
        for (int e = start + 64; e < end; ++e) {   // overflow path (deg > 64), effectively never
            float ex = __expf(lrelu(al_s2[csr_src[e]] + ald) - m);
            acc = fmaf(ex, bf2f(o1bf[csr_src[e] * 64 + lane]), acc);
        }
        lagg[r][lane] = f2bf(acc / dsum);
    }
    __syncthreads();
    // phase B: A[m=lane&15][k=quad*8+j] from LDS; B[k][n=lane&15] from W2bfT (n-major).
    int mcol = lane & 15;
    int q = lane >> 4;
    short8 a0 = *(const short8*)&lagg[mcol][q * 8];
    short8 a1 = *(const short8*)&lagg[mcol][32 + q * 8];
    int gmin = batch[n0], gmax = batch[n0 + 15];
    int batchq[4];
#pragma unroll
    for (int r = 0; r < 4; ++r) batchq[r] = batch[n0 + q * 4 + r];
#pragma unroll
    for (int t = 0; t < 4; ++t) {
        int c = w * 64 + t * 16 + mcol;
        const unsigned short* bp = W2bfT + c * 64 + q * 8;
        short8 b0 = *(const short8*)bp;
        short8 b1 = *(const short8*)(bp + 32);
        float4v acc = {0.f, 0.f, 0.f, 0.f};
        acc = __builtin_amdgcn_mfma_f32_16x16x32_bf16(a0, b0, acc, 0, 0, 0);
        acc = __builtin_amdgcn_mfma_f32_16x16x32_bf16(a1, b1, acc, 0, 0, 0);
        float bias = b2[c];
        float val[4];
#pragma unroll
        for (int r = 0; r < 4; ++r) val[r] = elu1(acc[r] + bias);
        for (int g = gmin; g <= gmax; ++g) {
            float s = 0.f;
#pragma unroll
            for (int r = 0; r < 4; ++r) s += (batchq[r] == g) ? val[r] : 0.f;
            s += __shfl_xor(s, 16, 64);   // reduce across the 4 quads
            s += __shfl_xor(s, 32, 64);
            if (q == 0) atomicAdd(&sums[g * 512 + c], s);
        }
    }
}

// ---------- D6: final GEMM: out[g][j] = (sums[g] @ Wo[:,j]) / cnt[g] + bo[j] ----------
__global__ void k_final(const float* __restrict__ sums, const int* __restrict__ gstart,
                        const float* __restrict__ Wo, const float* __restrict__ bo,
                        float* __restrict__ out) {
    __shared__ float sp[512];
    int g = blockIdx.x >> 3;
    int j = (blockIdx.x & 7) * 64 + threadIdx.x;  // 64 threads
    for (int k = threadIdx.x; k < 512; k += 64) sp[k] = sums[g * 512 + k];
    __syncthreads();
    float c = (float)(gstart[g + 1] - gstart[g]);
    float inv = 1.f / (c > 0.f ? c : 1.f);
    float acc = 0.f;
    for (int k = 0; k < 512; ++k) acc = fmaf(sp[k], Wo[k * 512 + j], acc);
    out[g * 512 + j] = fmaf(acc, inv, bo[j]);
}

extern "C" void kernel_launch(void* const* d_in, const int* in_sizes, int n_in,
                              void* d_out, int out_size, void* d_ws, size_t ws_size,
                              hipStream_t stream) {
    const float* x     = (const float*)d_in[0];
    const int*   ei    = (const int*)d_in[1];    // [2, NE]
    const int*   batch = (const int*)d_in[2];    // [NN] sorted
    const float* W1    = (const float*)d_in[3];
    const float* as1   = (const float*)d_in[4];
    const float* ad1   = (const float*)d_in[5];
    const float* b1    = (const float*)d_in[6];
    const float* W2    = (const float*)d_in[7];
    const float* as2   = (const float*)d_in[8];
    const float* ad2   = (const float*)d_in[9];
    const float* b2    = (const float*)d_in[10];
    const float* Wo    = (const float*)d_in[11];
    const float* bo    = (const float*)d_in[12];
    float* out = (float*)d_out;

    // ---- workspace arena (4-byte units) ----
    float* w = (float*)d_ws;
    unsigned short* h1bf  = (unsigned short*)(w + 0);        // 640,000 units
    float* al_s1 = w + 640000;     // 160,000
    float* al_d1 = w + 800000;     // 160,000
    unsigned short* o1bf  = (unsigned short*)(w + 960000);   // 640,000 units (byte 3,840,000: 16B aligned)
    unsigned short* W2bfT = (unsigned short*)(w + 1600000);  // 16,384 units (byte 6,400,000: 16B aligned)
    float* a2ps  = w + 1616384;    // 64
    float* a2pd  = w + 1616448;    // 64
    float* al_s2 = w + 1616512;    // 20,000
    float* al_d2 = w + 1636512;    // 20,000
    int*   rowstart = (int*)(w + 1656512);   // 20,001
    int*   cursor   = (int*)(w + 1676516);   // 20,000
    int*   csr_src  = (int*)(w + 1696516);   // 340,000
    int*   gstart   = (int*)(w + 2036516);   // 65
    // ---- zero-initialized region (one contiguous memset) ----
    int*   deg      = (int*)(w + 2036584);   // 20,000
    float* sums     = w + 2056584;           // 32,768
    // end: 2,089,352 units ≈ 8.4 MB

    hipMemsetAsync(w + 2036584, 0, (size_t)(20000 + 32768) * 4, stream);

    k_prep   <<<HB + CB + AB + NN / 4, 256, 0, stream>>>(ei, deg, W2, W2bfT, as2, ad2,
                                                         a2ps, a2pd, x, W1, as1, ad1,
                                                         h1bf, al_s1, al_d1);
    k_scan   <<<1, 1024, 0, stream>>>(deg, batch, rowstart, cursor, gstart);
    k_scatter<<<HB, 256, 0, stream>>>(ei, cursor, csr_src);
    k_l1     <<<NN / 4, 256, 0, stream>>>(rowstart, csr_src, al_s1, al_d1, h1bf, b1,
                                          a2ps, a2pd, o1bf, al_s2, al_d2);
    k_l2gemm <<<NN / 16, 512, 0, stream>>>(rowstart, csr_src, al_s2, al_d2, o1bf,
                                           W2bfT, b2, batch, sums);
    k_final  <<<NG * 8, 64, 0, stream>>>(sums, gstart, Wo, bo, out);
}

// Round 14
// 202.010 us; speedup vs baseline: 1.9417x; 1.0358x over previous
//
#include <hip/hip_runtime.h>
#include <math.h>

#define NN 20000      // nodes
#define NE 320000     // edges (without self loops)
#define NT 340000     // edges + self loops
#define NG 64         // graphs
#define HB 1329       // (NT+255)/256 hist/scatter blocks
#define CB 128        // W2->bf16 transpose blocks
#define AB 2          // a2p GEMV blocks

using short8  = __attribute__((ext_vector_type(8))) short;   // 8 x bf16 (4 VGPRs)
using float4v = __attribute__((ext_vector_type(4))) float;   // MFMA accumulator

__device__ __forceinline__ float lrelu(float v) { return v > 0.f ? v : 0.2f * v; }
__device__ __forceinline__ float elu1(float v)  { return v > 0.f ? v : (expf(v) - 1.f); }
__device__ __forceinline__ float bflo(unsigned u) { return __uint_as_float(u << 16); }
__device__ __forceinline__ float bfhi(unsigned u) { return __uint_as_float(u & 0xFFFF0000u); }
__device__ __forceinline__ unsigned short f2bf(float f) {
    unsigned u = __float_as_uint(f);
    u += 0x7FFFu + ((u >> 16) & 1u);   // round to nearest even
    return (unsigned short)(u >> 16);
}
__device__ __forceinline__ float bf2f(unsigned short s) {
    return __uint_as_float(((unsigned)s) << 16);
}

#define ACC8(ex, hv) \
    acc[0] = fmaf(ex, bflo(hv.x), acc[0]); \
    acc[1] = fmaf(ex, bfhi(hv.x), acc[1]); \
    acc[2] = fmaf(ex, bflo(hv.y), acc[2]); \
    acc[3] = fmaf(ex, bfhi(hv.y), acc[3]); \
    acc[4] = fmaf(ex, bflo(hv.z), acc[4]); \
    acc[5] = fmaf(ex, bfhi(hv.z), acc[5]); \
    acc[6] = fmaf(ex, bflo(hv.w), acc[6]); \
    acc[7] = fmaf(ex, bfhi(hv.w), acc[7]);

__device__ __forceinline__ int esrc(const int* ei, int e) { return e < NE ? ei[e] : (e - NE); }
__device__ __forceinline__ int edst(const int* ei, int e) { return e < NE ? ei[NE + e] : (e - NE); }

// ---------- D1: fused prep (all grid-parallel; no serial tail) ----------
__global__ void k_prep(const int* __restrict__ ei, int* __restrict__ deg,
                       const float* __restrict__ W2, unsigned short* __restrict__ W2bfT,
                       const float* __restrict__ as2, const float* __restrict__ ad2,
                       float* __restrict__ a2ps, float* __restrict__ a2pd,
                       const float* __restrict__ x, const float* __restrict__ W1,
                       const float* __restrict__ as1, const float* __restrict__ ad1,
                       unsigned short* __restrict__ h1bf, float* __restrict__ al_s,
                       float* __restrict__ al_d) {
    int tid = threadIdx.x;
    int b = blockIdx.x;
    if (b < HB) {
        int t = b * 256 + tid;
        if (t < NE) atomicAdd(&deg[ei[NE + t]], 1);
        return;
    }
    if (b < HB + CB) {
        int t = (b - HB) * 256 + tid;  // t = n*64 + k
        int k = t & 63, n = t >> 6;
        W2bfT[t] = f2bf(W2[k * 512 + n]);
        return;
    }
    if (b < HB + CB + AB) {
        // a2p[k] = sum_j W2[k][j] * a[j]   (64x512 GEMV)
        __shared__ float pp[4][64];
        const float* av = (b == HB + CB) ? as2 : ad2;
        float* outp     = (b == HB + CB) ? a2ps : a2pd;
        int k = tid & 63, seg = tid >> 6;
        float s = 0.f;
        for (int j = seg * 128; j < seg * 128 + 128; ++j)
            s = fmaf(W2[k * 512 + j], av[j], s);
        pp[seg][k] = s;
        __syncthreads();
        if (tid < 64) outp[tid] = pp[0][tid] + pp[1][tid] + pp[2][tid] + pp[3][tid];
        return;
    }
    int n = (b - HB - CB - AB) * 4 + (tid >> 6);
    int j = tid & 63;
    float x0 = x[n * 3 + 0], x1 = x[n * 3 + 1], x2 = x[n * 3 + 2];
    float v = fmaf(x0, W1[j], fmaf(x1, W1[64 + j], x2 * W1[128 + j]));
    h1bf[n * 64 + j] = f2bf(v);
    float ps = v * as1[j];
    float pd = v * ad1[j];
    for (int o = 4; o >= 1; o >>= 1) {
        ps += __shfl_xor(ps, o, 8);
        pd += __shfl_xor(pd, o, 8);
    }
    if ((j & 7) == 0) {
        al_s[n * 8 + (j >> 3)] = ps;
        al_d[n * 8 + (j >> 3)] = pd;
    }
}

// ---------- D2: single-block scan (plain cached loads, L2-hot) ----------
__global__ void k_scan(const int* __restrict__ deg, const int* __restrict__ batch,
                       int* __restrict__ rowstart, int* __restrict__ cursor,
                       int* __restrict__ gstart) {
    __shared__ int part[1024];
    int t = threadIdx.x;
    int base = t * 20;
    int local[20];
    int s = 0;
    if (base < NN) {
#pragma unroll
        for (int i = 0; i < 20; ++i) { local[i] = deg[base + i] + 1; s += local[i]; }
    }
    part[t] = s;
    __syncthreads();
    for (int o = 1; o < 1024; o <<= 1) {
        int v = (t >= o) ? part[t - o] : 0;
        __syncthreads();
        part[t] += v;
        __syncthreads();
    }
    if (base < NN) {
        int run = (t == 0) ? 0 : part[t - 1];
#pragma unroll
        for (int i = 0; i < 20; ++i) {
            rowstart[base + i] = run;
            cursor[base + i] = run;
            run += local[i];
        }
    }
    if (t == 1023) rowstart[NN] = NT;
    if (t <= NG) {
        int lo = 0, hi = NN;
        while (lo < hi) {
            int mid = (lo + hi) >> 1;
            if (batch[mid] < t) lo = mid + 1; else hi = mid;
        }
        gstart[t] = lo;
    }
}

// ---------- D3: CSR scatter ----------
__global__ void k_scatter(const int* __restrict__ ei, int* __restrict__ cursor,
                          int* __restrict__ csr_src) {
    int t = blockIdx.x * blockDim.x + threadIdx.x;
    if (t >= NT) return;
    int d = edst(ei, t), s = esrc(ei, t);
    int pos = atomicAdd(&cursor[d], 1);
    csr_src[pos] = s;
}

// ---------- D4: fused layer-1 softmax + aggregate + bias + elu -> o1bf; layer-2 logits ----------
// 4 nodes/block (1 wave each). Softmax lane-parallel into LDS. Aggregate in edge-octet layout:
// lane=(e8,c8); 8 edges/iteration, each lane gathers a contiguous 16B slice (head c8's channels).
__global__ void k_l1(const int* __restrict__ rowstart, const int* __restrict__ csr_src,
                     const float* __restrict__ al_s, const float* __restrict__ al_d,
                     const unsigned short* __restrict__ h1bf, const float* __restrict__ b1,
                     const float* __restrict__ a2ps, const float* __restrict__ a2pd,
                     unsigned short* __restrict__ o1bf, float* __restrict__ al_s2,
                     float* __restrict__ al_d2) {
    __shared__ float lex1[4][8][69];   // [node][head][edge-slot], pad 69 -> 2-way banks max
    __shared__ float ldsum[4][8];
    __shared__ float lmax[4][8];
    int nb = threadIdx.x >> 6;
    int n = blockIdx.x * 4 + nb;
    int lane = threadIdx.x & 63;
    int h = lane >> 3, sub = lane & 7;   // softmax-phase mapping (8 lanes per head)
    float ald = al_d[n * 8 + h];
    int start = rowstart[n], end = rowstart[n + 1];
    int deg = end - start;
    // pass 1: per-head max
    float m = -1e30f;
    for (int e = start + sub; e < end; e += 8)
        m = fmaxf(m, lrelu(al_s[csr_src[e] * 8 + h] + ald));
    for (int o = 4; o >= 1; o >>= 1) m = fmaxf(m, __shfl_xor(m, o, 8));
    // pass 2: exp + per-head denom; cache first 64 slots
    float dsum = 0.f;
    {
        int idx = 0;
        for (int e = start + sub; e < end; e += 8, ++idx) {
            float ex = __expf(lrelu(al_s[csr_src[e] * 8 + h] + ald) - m);
            dsum += ex;
            if (idx < 8) lex1[nb][h][sub + idx * 8] = ex;
        }
    }
    for (int o = 4; o >= 1; o >>= 1) dsum += __shfl_xor(dsum, o, 8);
    if (sub == 0) { ldsum[nb][h] = dsum; lmax[nb][h] = m; }
    // aggregate, octet layout: e8 = lane>>3 (edge slot), c8 = lane&7 (= head)
    int e8 = lane >> 3, c8 = lane & 7;
    float mh = lmax[nb][c8];
    float aldc = (deg > 64) ? al_d[n * 8 + c8] : 0.f;
    float acc[8] = {0.f, 0.f, 0.f, 0.f, 0.f, 0.f, 0.f, 0.f};
    for (int base = 0; base < deg; base += 16) {
        int slotA = base + e8;
        int slotB = base + 8 + e8;
        float exA = 0.f, exB = 0.f;
        if (base < 64) {
            if (slotA < deg) exA = lex1[nb][c8][slotA];
        } else if (slotA < deg) {
            exA = __expf(lrelu(al_s[csr_src[start + slotA] * 8 + c8] + aldc) - mh);
        }
        if (base + 8 < 64) {
            if (slotB < deg) exB = lex1[nb][c8][slotB];
        } else if (slotB < deg) {
            exB = __expf(lrelu(al_s[csr_src[start + slotB] * 8 + c8] + aldc) - mh);
        }
        int sA = csr_src[start + (slotA < deg ? slotA : 0)];
        int sB = csr_src[start + (slotB < deg ? slotB : 0)];
        uint4 hA = *(const uint4*)(h1bf + sA * 64 + c8 * 8);
        uint4 hB = *(const uint4*)(h1bf + sB * 64 + c8 * 8);
        ACC8(exA, hA);
        ACC8(exB, hB);
    }
    // reduce across the 8 edge slots (lane bits 3..5)
#pragma unroll
    for (int o = 32; o >= 8; o >>= 1) {
#pragma unroll
        for (int k = 0; k < 8; ++k) acc[k] += __shfl_xor(acc[k], o, 64);
    }
    if (e8 == 0) {   // lanes 0..7: finalize head c8's 8 channels
        float inv = 1.f / ldsum[nb][c8];
        const float* bp = b1 + c8 * 8;
        float v[8];
#pragma unroll
        for (int k = 0; k < 8; ++k) v[k] = elu1(acc[k] * inv + bp[k]);
        uint4 pk;
        pk.x = (unsigned)f2bf(v[0]) | ((unsigned)f2bf(v[1]) << 16);
        pk.y = (unsigned)f2bf(v[2]) | ((unsigned)f2bf(v[3]) << 16);
        pk.z = (unsigned)f2bf(v[4]) | ((unsigned)f2bf(v[5]) << 16);
        pk.w = (unsigned)f2bf(v[6]) | ((unsigned)f2bf(v[7]) << 16);
        *(uint4*)(o1bf + n * 64 + c8 * 8) = pk;
        float ps = 0.f, pd = 0.f;
        const float* asp = a2ps + c8 * 8;
        const float* adp = a2pd + c8 * 8;
#pragma unroll
        for (int k = 0; k < 8; ++k) {
            ps = fmaf(v[k], asp[k], ps);
            pd = fmaf(v[k], adp[k], pd);
        }
        for (int o = 4; o >= 1; o >>= 1) {
            ps += __shfl_xor(ps, o, 8);
            pd += __shfl_xor(pd, o, 8);
        }
        if (c8 == 0) { al_s2[n] = ps; al_d2[n] = pd; }
    }
}

// ---------- D5: fused layer-2 softmax-agg (64-dim, octet layout) + MFMA @W2 + elu + pool ----------
// 16 nodes/block, 512 threads (8 waves). Phase A: wave w handles nodes w*2,w*2+1.
// Phase B: MFMA (A from LDS, B from W2bfT), elu, graph-masked pool -> atomics into sums.
__global__ void k_l2gemm(const int* __restrict__ rowstart, const int* __restrict__ csr_src,
                         const float* __restrict__ al_s2, const float* __restrict__ al_d2,
                         const unsigned short* __restrict__ o1bf,
                         const unsigned short* __restrict__ W2bfT,
                         const float* __restrict__ b2, const int* __restrict__ batch,
                         float* __restrict__ sums) {
    __shared__ unsigned short lagg[16][72];   // padded rows: 144B stride
    __shared__ float lex[16][64];             // per-node cached edge exps (intra-wave)
    int n0 = blockIdx.x * 16;
    int w = threadIdx.x >> 6, lane = threadIdx.x & 63;
    int e8 = lane >> 3, c8 = lane & 7;
#pragma unroll
    for (int i = 0; i < 2; ++i) {
        int r = w * 2 + i;
        int n = n0 + r;
        float ald = al_d2[n];
        int start = rowstart[n], end = rowstart[n + 1];
        int deg = end - start;
        // pass 1 (lane-parallel): max
        float m = -1e30f;
        for (int e = start + lane; e < end; e += 64)
            m = fmaxf(m, lrelu(al_s2[csr_src[e]] + ald));
        for (int o = 32; o >= 1; o >>= 1) m = fmaxf(m, __shfl_xor(m, o, 64));
        // pass 2: ex + denom via shuffle; cache first 64 in LDS
        float dsum = 0.f;
        {
            int idx = 0;
            for (int e = start + lane; e < end; e += 64, ++idx) {
                float ex = __expf(lrelu(al_s2[csr_src[e]] + ald) - m);
                dsum += ex;
                if (idx == 0) lex[r][lane] = ex;
            }
        }
        for (int o = 32; o >= 1; o >>= 1) dsum += __shfl_xor(dsum, o, 64);
        // octet aggregation: 8 edges per iteration, 16B gather per lane
        float acc[8] = {0.f, 0.f, 0.f, 0.f, 0.f, 0.f, 0.f, 0.f};
        for (int base = 0; base < deg; base += 16) {
            int slotA = base + e8;
            int slotB = base + 8 + e8;
            float exA = 0.f, exB = 0.f;
            if (base < 64) {
                if (slotA < deg) exA = lex[r][slotA];
            } else if (slotA < deg) {
                exA = __expf(lrelu(al_s2[csr_src[start + slotA]] + ald) - m);
            }
            if (base + 8 < 64) {
                if (slotB < deg) exB = lex[r][slotB];
            } else if (slotB < deg) {
                exB = __expf(lrelu(al_s2[csr_src[start + slotB]] + ald) - m);
            }
            int sA = csr_src[start + (slotA < deg ? slotA : 0)];
            int sB = csr_src[start + (slotB < deg ? slotB : 0)];
            uint4 hA = *(const uint4*)(o1bf + sA * 64 + c8 * 8);
            uint4 hB = *(const uint4*)(o1bf + sB * 64 + c8 * 8);
            ACC8(exA, hA);
            ACC8(exB, hB);
        }
#pragma unroll
        for (int o = 32; o >= 8; o >>= 1) {
#pragma unroll
            for (int k = 0; k < 8; ++k) acc[k] += __shfl_xor(acc[k], o, 64);
        }
        if (e8 == 0) {   // lanes 0..7 pack channels c8*8..+7
            float inv = 1.f / dsum;
            uint4 pk;
            pk.x = (unsigned)f2bf(acc[0] * inv) | ((unsigned)f2bf(acc[1] * inv) << 16);
            pk.y = (unsigned)f2bf(acc[2] * inv) | ((unsigned)f2bf(acc[3] * inv) << 16);
            pk.z = (unsigned)f2bf(acc[4] * inv) | ((unsigned)f2bf(acc[5] * inv) << 16);
            pk.w = (unsigned)f2bf(acc[6] * inv) | ((unsigned)f2bf(acc[7] * inv) << 16);
            *(uint4*)&lagg[r][c8 * 8] = pk;
        }
    }
    __syncthreads();
    // phase B: A[m=lane&15][k=quad*8+j] from LDS; B[k][n=lane&15] from W2bfT (n-major).
    int mcol = lane & 15;
    int q = lane >> 4;
    short8 a0 = *(const short8*)&lagg[mcol][q * 8];
    short8 a1 = *(const short8*)&lagg[mcol][32 + q * 8];
    int gmin = batch[n0], gmax = batch[n0 + 15];
    int batchq[4];
#pragma unroll
    for (int r = 0; r < 4; ++r) batchq[r] = batch[n0 + q * 4 + r];
#pragma unroll
    for (int t = 0; t < 4; ++t) {
        int c = w * 64 + t * 16 + mcol;
        const unsigned short* bp = W2bfT + c * 64 + q * 8;
        short8 b0 = *(const short8*)bp;
        short8 b1v = *(const short8*)(bp + 32);
        float4v acc = {0.f, 0.f, 0.f, 0.f};
        acc = __builtin_amdgcn_mfma_f32_16x16x32_bf16(a0, b0, acc, 0, 0, 0);
        acc = __builtin_amdgcn_mfma_f32_16x16x32_bf16(a1, b1v, acc, 0, 0, 0);
        float bias = b2[c];
        float val[4];
#pragma unroll
        for (int r = 0; r < 4; ++r) val[r] = elu1(acc[r] + bias);
        for (int g = gmin; g <= gmax; ++g) {
            float s = 0.f;
#pragma unroll
            for (int r = 0; r < 4; ++r) s += (batchq[r] == g) ? val[r] : 0.f;
            s += __shfl_xor(s, 16, 64);   // reduce across the 4 quads
            s += __shfl_xor(s, 32, 64);
            if (q == 0) atomicAdd(&sums[g * 512 + c], s);
        }
    }
}

// ---------- D6: final GEMM: out[g][j] = (sums[g] @ Wo[:,j]) / cnt[g] + bo[j] ----------
__global__ void k_final(const float* __restrict__ sums, const int* __restrict__ gstart,
                        const float* __restrict__ Wo, const float* __restrict__ bo,
                        float* __restrict__ out) {
    __shared__ float sp[512];
    int g = blockIdx.x >> 3;
    int j = (blockIdx.x & 7) * 64 + threadIdx.x;  // 64 threads
    for (int k = threadIdx.x; k < 512; k += 64) sp[k] = sums[g * 512 + k];
    __syncthreads();
    float c = (float)(gstart[g + 1] - gstart[g]);
    float inv = 1.f / (c > 0.f ? c : 1.f);
    float acc = 0.f;
    for (int k = 0; k < 512; ++k) acc = fmaf(sp[k], Wo[k * 512 + j], acc);
    out[g * 512 + j] = fmaf(acc, inv, bo[j]);
}

extern "C" void kernel_launch(void* const* d_in, const int* in_sizes, int n_in,
                              void* d_out, int out_size, void* d_ws, size_t ws_size,
                              hipStream_t stream) {
    const float* x     = (const float*)d_in[0];
    const int*   ei    = (const int*)d_in[1];    // [2, NE]
    const int*   batch = (const int*)d_in[2];    // [NN] sorted
    const float* W1    = (const float*)d_in[3];
    const float* as1   = (const float*)d_in[4];
    const float* ad1   = (const float*)d_in[5];
    const float* b1    = (const float*)d_in[6];
    const float* W2    = (const float*)d_in[7];
    const float* as2   = (const float*)d_in[8];
    const float* ad2   = (const float*)d_in[9];
    const float* b2    = (const float*)d_in[10];
    const float* Wo    = (const float*)d_in[11];
    const float* bo    = (const float*)d_in[12];
    float* out = (float*)d_out;

    // ---- workspace arena (4-byte units) ----
    float* w = (float*)d_ws;
    unsigned short* h1bf  = (unsigned short*)(w + 0);        // 640,000 units
    float* al_s1 = w + 640000;     // 160,000
    float* al_d1 = w + 800000;     // 160,000
    unsigned short* o1bf  = (unsigned short*)(w + 960000);   // 640,000 units (byte 3,840,000: 16B aligned)
    unsigned short* W2bfT = (unsigned short*)(w + 1600000);  // 16,384 units (byte 6,400,000: 16B aligned)
    float* a2ps  = w + 1616384;    // 64
    float* a2pd  = w + 1616448;    // 64
    float* al_s2 = w + 1616512;    // 20,000
    float* al_d2 = w + 1636512;    // 20,000
    int*   rowstart = (int*)(w + 1656512);   // 20,001
    int*   cursor   = (int*)(w + 1676516);   // 20,000
    int*   csr_src  = (int*)(w + 1696516);   // 340,000
    int*   gstart   = (int*)(w + 2036516);   // 65
    // ---- zero-initialized region (one contiguous memset) ----
    int*   deg      = (int*)(w + 2036584);   // 20,000
    float* sums     = w + 2056584;           // 32,768
    // end: 2,089,352 units ≈ 8.4 MB

    hipMemsetAsync(w + 2036584, 0, (size_t)(20000 + 32768) * 4, stream);

    k_prep   <<<HB + CB + AB + NN / 4, 256, 0, stream>>>(ei, deg, W2, W2bfT, as2, ad2,
                                                         a2ps, a2pd, x, W1, as1, ad1,
                                                         h1bf, al_s1, al_d1);
    k_scan   <<<1, 1024, 0, stream>>>(deg, batch, rowstart, cursor, gstart);
    k_scatter<<<HB, 256, 0, stream>>>(ei, cursor, csr_src);
    k_l1     <<<NN / 4, 256, 0, stream>>>(rowstart, csr_src, al_s1, al_d1, h1bf, b1,
                                          a2ps, a2pd, o1bf, al_s2, al_d2);
    k_l2gemm <<<NN / 16, 512, 0, stream>>>(rowstart, csr_src, al_s2, al_d2, o1bf,
                                           W2bfT, b2, batch, sums);
    k_final  <<<NG * 8, 64, 0, stream>>>(sums, gstart, Wo, bo, out);
}

// Round 15
// 194.919 us; speedup vs baseline: 2.0124x; 1.0364x over previous
//
#include <hip/hip_runtime.h>
#include <math.h>

#define NN 20000      // nodes
#define NE 320000     // edges (without self loops)
#define NT 340000     // edges + self loops
#define NG 64         // graphs
#define HB 1329       // (NT+255)/256 hist/scatter blocks
#define CB 128        // W2->bf16 transpose blocks
#define AB 2          // a2p GEMV blocks

using short8  = __attribute__((ext_vector_type(8))) short;   // 8 x bf16 (4 VGPRs)
using float4v = __attribute__((ext_vector_type(4))) float;   // MFMA accumulator

__device__ __forceinline__ float lrelu(float v) { return v > 0.f ? v : 0.2f * v; }
__device__ __forceinline__ float elu1(float v)  { return v > 0.f ? v : (expf(v) - 1.f); }
__device__ __forceinline__ float bflo(unsigned u) { return __uint_as_float(u << 16); }
__device__ __forceinline__ float bfhi(unsigned u) { return __uint_as_float(u & 0xFFFF0000u); }
__device__ __forceinline__ unsigned short f2bf(float f) {
    unsigned u = __float_as_uint(f);
    u += 0x7FFFu + ((u >> 16) & 1u);   // round to nearest even
    return (unsigned short)(u >> 16);
}
__device__ __forceinline__ float bf2f(unsigned short s) {
    return __uint_as_float(((unsigned)s) << 16);
}

#define ACC8(ex, hv) \
    acc[0] = fmaf(ex, bflo(hv.x), acc[0]); \
    acc[1] = fmaf(ex, bfhi(hv.x), acc[1]); \
    acc[2] = fmaf(ex, bflo(hv.y), acc[2]); \
    acc[3] = fmaf(ex, bfhi(hv.y), acc[3]); \
    acc[4] = fmaf(ex, bflo(hv.z), acc[4]); \
    acc[5] = fmaf(ex, bfhi(hv.z), acc[5]); \
    acc[6] = fmaf(ex, bflo(hv.w), acc[6]); \
    acc[7] = fmaf(ex, bfhi(hv.w), acc[7]);

__device__ __forceinline__ int esrc(const int* ei, int e) { return e < NE ? ei[e] : (e - NE); }
__device__ __forceinline__ int edst(const int* ei, int e) { return e < NE ? ei[NE + e] : (e - NE); }

// ---------- D1: fused prep (all grid-parallel; no serial tail) ----------
__global__ void k_prep(const int* __restrict__ ei, int* __restrict__ deg,
                       const float* __restrict__ W2, unsigned short* __restrict__ W2bfT,
                       const float* __restrict__ as2, const float* __restrict__ ad2,
                       float* __restrict__ a2ps, float* __restrict__ a2pd,
                       const float* __restrict__ x, const float* __restrict__ W1,
                       const float* __restrict__ as1, const float* __restrict__ ad1,
                       unsigned short* __restrict__ h1bf, float* __restrict__ al_s,
                       float* __restrict__ al_d) {
    int tid = threadIdx.x;
    int b = blockIdx.x;
    if (b < HB) {
        int t = b * 256 + tid;
        if (t < NE) atomicAdd(&deg[ei[NE + t]], 1);
        return;
    }
    if (b < HB + CB) {
        int t = (b - HB) * 256 + tid;  // t = n*64 + k
        int k = t & 63, n = t >> 6;
        W2bfT[t] = f2bf(W2[k * 512 + n]);
        return;
    }
    if (b < HB + CB + AB) {
        // a2p[k] = sum_j W2[k][j] * a[j]   (64x512 GEMV)
        __shared__ float pp[4][64];
        const float* av = (b == HB + CB) ? as2 : ad2;
        float* outp     = (b == HB + CB) ? a2ps : a2pd;
        int k = tid & 63, seg = tid >> 6;
        float s = 0.f;
        for (int j = seg * 128; j < seg * 128 + 128; ++j)
            s = fmaf(W2[k * 512 + j], av[j], s);
        pp[seg][k] = s;
        __syncthreads();
        if (tid < 64) outp[tid] = pp[0][tid] + pp[1][tid] + pp[2][tid] + pp[3][tid];
        return;
    }
    int n = (b - HB - CB - AB) * 4 + (tid >> 6);
    int j = tid & 63;
    float x0 = x[n * 3 + 0], x1 = x[n * 3 + 1], x2 = x[n * 3 + 2];
    float v = fmaf(x0, W1[j], fmaf(x1, W1[64 + j], x2 * W1[128 + j]));
    h1bf[n * 64 + j] = f2bf(v);
    float ps = v * as1[j];
    float pd = v * ad1[j];
    for (int o = 4; o >= 1; o >>= 1) {
        ps += __shfl_xor(ps, o, 8);
        pd += __shfl_xor(pd, o, 8);
    }
    if ((j & 7) == 0) {
        al_s[n * 8 + (j >> 3)] = ps;
        al_d[n * 8 + (j >> 3)] = pd;
    }
}

// ---------- D2: single-block scan (plain cached loads, L2-hot) ----------
__global__ void k_scan(const int* __restrict__ deg, const int* __restrict__ batch,
                       int* __restrict__ rowstart, int* __restrict__ cursor,
                       int* __restrict__ gstart) {
    __shared__ int part[1024];
    int t = threadIdx.x;
    int base = t * 20;
    int local[20];
    int s = 0;
    if (base < NN) {
#pragma unroll
        for (int i = 0; i < 20; ++i) { local[i] = deg[base + i] + 1; s += local[i]; }
    }
    part[t] = s;
    __syncthreads();
    for (int o = 1; o < 1024; o <<= 1) {
        int v = (t >= o) ? part[t - o] : 0;
        __syncthreads();
        part[t] += v;
        __syncthreads();
    }
    if (base < NN) {
        int run = (t == 0) ? 0 : part[t - 1];
#pragma unroll
        for (int i = 0; i < 20; ++i) {
            rowstart[base + i] = run;
            cursor[base + i] = run;
            run += local[i];
        }
    }
    if (t == 1023) rowstart[NN] = NT;
    if (t <= NG) {
        int lo = 0, hi = NN;
        while (lo < hi) {
            int mid = (lo + hi) >> 1;
            if (batch[mid] < t) lo = mid + 1; else hi = mid;
        }
        gstart[t] = lo;
    }
}

// ---------- D3: CSR scatter ----------
__global__ void k_scatter(const int* __restrict__ ei, int* __restrict__ cursor,
                          int* __restrict__ csr_src) {
    int t = blockIdx.x * blockDim.x + threadIdx.x;
    if (t >= NT) return;
    int d = edst(ei, t), s = esrc(ei, t);
    int pos = atomicAdd(&cursor[d], 1);
    csr_src[pos] = s;
}

// ---------- D4: fused layer-1 softmax+aggregate (single pass, no max-sub) + elu; l2 logits ----
// 4 nodes/block (1 wave each). Octet layout: lane=(e8,c8); c8 = head. Each lane computes its
// edge's ex inline (logits O(+-5): exp safe without max shift), accumulates dsum + acc[8];
// one shuffle tree reduces all 9 values over the e8 bits.
__global__ void k_l1(const int* __restrict__ rowstart, const int* __restrict__ csr_src,
                     const float* __restrict__ al_s, const float* __restrict__ al_d,
                     const unsigned short* __restrict__ h1bf, const float* __restrict__ b1,
                     const float* __restrict__ a2ps, const float* __restrict__ a2pd,
                     unsigned short* __restrict__ o1bf, float* __restrict__ al_s2,
                     float* __restrict__ al_d2) {
    int nb = threadIdx.x >> 6;
    int n = blockIdx.x * 4 + nb;
    int lane = threadIdx.x & 63;
    int e8 = lane >> 3, c8 = lane & 7;   // edge slot, head
    int start = rowstart[n], end = rowstart[n + 1];
    int deg = end - start;
    float ald = al_d[n * 8 + c8];
    float acc[8] = {0.f, 0.f, 0.f, 0.f, 0.f, 0.f, 0.f, 0.f};
    float dsum = 0.f;
    for (int base = 0; base < deg; base += 16) {
        int slotA = base + e8;
        int slotB = base + 8 + e8;
        int sA = csr_src[start + (slotA < deg ? slotA : 0)];
        int sB = csr_src[start + (slotB < deg ? slotB : 0)];
        float exA = 0.f, exB = 0.f;
        if (slotA < deg) exA = __expf(lrelu(al_s[sA * 8 + c8] + ald));
        if (slotB < deg) exB = __expf(lrelu(al_s[sB * 8 + c8] + ald));
        dsum += exA + exB;
        uint4 hA = *(const uint4*)(h1bf + sA * 64 + c8 * 8);
        uint4 hB = *(const uint4*)(h1bf + sB * 64 + c8 * 8);
        ACC8(exA, hA);
        ACC8(exB, hB);
    }
    // reduce acc[8] + dsum across the 8 edge slots (lane bits 3..5)
#pragma unroll
    for (int o = 32; o >= 8; o >>= 1) {
#pragma unroll
        for (int k = 0; k < 8; ++k) acc[k] += __shfl_xor(acc[k], o, 64);
        dsum += __shfl_xor(dsum, o, 64);
    }
    if (e8 == 0) {   // lanes 0..7: finalize head c8's 8 channels
        float inv = 1.f / dsum;
        const float* bp = b1 + c8 * 8;
        float v[8];
#pragma unroll
        for (int k = 0; k < 8; ++k) v[k] = elu1(acc[k] * inv + bp[k]);
        uint4 pk;
        pk.x = (unsigned)f2bf(v[0]) | ((unsigned)f2bf(v[1]) << 16);
        pk.y = (unsigned)f2bf(v[2]) | ((unsigned)f2bf(v[3]) << 16);
        pk.z = (unsigned)f2bf(v[4]) | ((unsigned)f2bf(v[5]) << 16);
        pk.w = (unsigned)f2bf(v[6]) | ((unsigned)f2bf(v[7]) << 16);
        *(uint4*)(o1bf + n * 64 + c8 * 8) = pk;
        float ps = 0.f, pd = 0.f;
        const float* asp = a2ps + c8 * 8;
        const float* adp = a2pd + c8 * 8;
#pragma unroll
        for (int k = 0; k < 8; ++k) {
            ps = fmaf(v[k], asp[k], ps);
            pd = fmaf(v[k], adp[k], pd);
        }
        for (int o = 4; o >= 1; o >>= 1) {
            ps += __shfl_xor(ps, o, 8);
            pd += __shfl_xor(pd, o, 8);
        }
        if (c8 == 0) { al_s2[n] = ps; al_d2[n] = pd; }
    }
}

// ---------- D5: fused layer-2 softmax-agg (single pass, octet) + MFMA @W2 + elu + pool ------
// 16 nodes/block, 512 threads (8 waves). Phase A: wave w handles nodes w*2,w*2+1, ex inline.
// Phase B: MFMA (A from LDS, B from W2bfT), elu, graph-masked pool -> atomics into sums.
__global__ void k_l2gemm(const int* __restrict__ rowstart, const int* __restrict__ csr_src,
                         const float* __restrict__ al_s2, const float* __restrict__ al_d2,
                         const unsigned short* __restrict__ o1bf,
                         const unsigned short* __restrict__ W2bfT,
                         const float* __restrict__ b2, const int* __restrict__ batch,
                         float* __restrict__ sums) {
    __shared__ unsigned short lagg[16][72];   // padded rows: 144B stride
    int n0 = blockIdx.x * 16;
    int w = threadIdx.x >> 6, lane = threadIdx.x & 63;
    int e8 = lane >> 3, c8 = lane & 7;
#pragma unroll
    for (int i = 0; i < 2; ++i) {
        int r = w * 2 + i;
        int n = n0 + r;
        float ald = al_d2[n];
        int start = rowstart[n], end = rowstart[n + 1];
        int deg = end - start;
        float acc[8] = {0.f, 0.f, 0.f, 0.f, 0.f, 0.f, 0.f, 0.f};
        float dsum = 0.f;
        for (int base = 0; base < deg; base += 16) {
            int slotA = base + e8;
            int slotB = base + 8 + e8;
            int sA = csr_src[start + (slotA < deg ? slotA : 0)];
            int sB = csr_src[start + (slotB < deg ? slotB : 0)];
            float exA = 0.f, exB = 0.f;
            if (slotA < deg) exA = __expf(lrelu(al_s2[sA] + ald));
            if (slotB < deg) exB = __expf(lrelu(al_s2[sB] + ald));
            dsum += exA + exB;
            uint4 hA = *(const uint4*)(o1bf + sA * 64 + c8 * 8);
            uint4 hB = *(const uint4*)(o1bf + sB * 64 + c8 * 8);
            ACC8(exA, hA);
            ACC8(exB, hB);
        }
#pragma unroll
        for (int o = 32; o >= 8; o >>= 1) {
#pragma unroll
            for (int k = 0; k < 8; ++k) acc[k] += __shfl_xor(acc[k], o, 64);
            dsum += __shfl_xor(dsum, o, 64);
        }
        if (e8 == 0) {   // lanes 0..7 pack channels c8*8..+7
            float inv = 1.f / dsum;
            uint4 pk;
            pk.x = (unsigned)f2bf(acc[0] * inv) | ((unsigned)f2bf(acc[1] * inv) << 16);
            pk.y = (unsigned)f2bf(acc[2] * inv) | ((unsigned)f2bf(acc[3] * inv) << 16);
            pk.z = (unsigned)f2bf(acc[4] * inv) | ((unsigned)f2bf(acc[5] * inv) << 16);
            pk.w = (unsigned)f2bf(acc[6] * inv) | ((unsigned)f2bf(acc[7] * inv) << 16);
            *(uint4*)&lagg[r][c8 * 8] = pk;
        }
    }
    __syncthreads();
    // phase B: A[m=lane&15][k=quad*8+j] from LDS; B[k][n=lane&15] from W2bfT (n-major).
    int mcol = lane & 15;
    int q = lane >> 4;
    short8 a0 = *(const short8*)&lagg[mcol][q * 8];
    short8 a1 = *(const short8*)&lagg[mcol][32 + q * 8];
    int gmin = batch[n0], gmax = batch[n0 + 15];
    int batchq[4];
#pragma unroll
    for (int r = 0; r < 4; ++r) batchq[r] = batch[n0 + q * 4 + r];
#pragma unroll
    for (int t = 0; t < 4; ++t) {
        int c = w * 64 + t * 16 + mcol;
        const unsigned short* bp = W2bfT + c * 64 + q * 8;
        short8 b0 = *(const short8*)bp;
        short8 b1v = *(const short8*)(bp + 32);
        float4v acc = {0.f, 0.f, 0.f, 0.f};
        acc = __builtin_amdgcn_mfma_f32_16x16x32_bf16(a0, b0, acc, 0, 0, 0);
        acc = __builtin_amdgcn_mfma_f32_16x16x32_bf16(a1, b1v, acc, 0, 0, 0);
        float bias = b2[c];
        float val[4];
#pragma unroll
        for (int r = 0; r < 4; ++r) val[r] = elu1(acc[r] + bias);
        for (int g = gmin; g <= gmax; ++g) {
            float s = 0.f;
#pragma unroll
            for (int r = 0; r < 4; ++r) s += (batchq[r] == g) ? val[r] : 0.f;
            s += __shfl_xor(s, 16, 64);   // reduce across the 4 quads
            s += __shfl_xor(s, 32, 64);
            if (q == 0) atomicAdd(&sums[g * 512 + c], s);
        }
    }
}

// ---------- D6: final GEMM: out[g][j] = (sums[g] @ Wo[:,j]) / cnt[g] + bo[j] ----------
__global__ void k_final(const float* __restrict__ sums, const int* __restrict__ gstart,
                        const float* __restrict__ Wo, const float* __restrict__ bo,
                        float* __restrict__ out) {
    __shared__ float sp[512];
    int g = blockIdx.x >> 3;
    int j = (blockIdx.x & 7) * 64 + threadIdx.x;  // 64 threads
    for (int k = threadIdx.x; k < 512; k += 64) sp[k] = sums[g * 512 + k];
    __syncthreads();
    float c = (float)(gstart[g + 1] - gstart[g]);
    float inv = 1.f / (c > 0.f ? c : 1.f);
    float acc = 0.f;
    for (int k = 0; k < 512; ++k) acc = fmaf(sp[k], Wo[k * 512 + j], acc);
    out[g * 512 + j] = fmaf(acc, inv, bo[j]);
}

extern "C" void kernel_launch(void* const* d_in, const int* in_sizes, int n_in,
                              void* d_out, int out_size, void* d_ws, size_t ws_size,
                              hipStream_t stream) {
    const float* x     = (const float*)d_in[0];
    const int*   ei    = (const int*)d_in[1];    // [2, NE]
    const int*   batch = (const int*)d_in[2];    // [NN] sorted
    const float* W1    = (const float*)d_in[3];
    const float* as1   = (const float*)d_in[4];
    const float* ad1   = (const float*)d_in[5];
    const float* b1    = (const float*)d_in[6];
    const float* W2    = (const float*)d_in[7];
    const float* as2   = (const float*)d_in[8];
    const float* ad2   = (const float*)d_in[9];
    const float* b2    = (const float*)d_in[10];
    const float* Wo    = (const float*)d_in[11];
    const float* bo    = (const float*)d_in[12];
    float* out = (float*)d_out;

    // ---- workspace arena (4-byte units) ----
    float* w = (float*)d_ws;
    unsigned short* h1bf  = (unsigned short*)(w + 0);        // 640,000 units
    float* al_s1 = w + 640000;     // 160,000
    float* al_d1 = w + 800000;     // 160,000
    unsigned short* o1bf  = (unsigned short*)(w + 960000);   // 640,000 units (byte 3,840,000: 16B aligned)
    unsigned short* W2bfT = (unsigned short*)(w + 1600000);  // 16,384 units (byte 6,400,000: 16B aligned)
    float* a2ps  = w + 1616384;    // 64
    float* a2pd  = w + 1616448;    // 64
    float* al_s2 = w + 1616512;    // 20,000
    float* al_d2 = w + 1636512;    // 20,000
    int*   rowstart = (int*)(w + 1656512);   // 20,001
    int*   cursor   = (int*)(w + 1676516);   // 20,000
    int*   csr_src  = (int*)(w + 1696516);   // 340,000
    int*   gstart   = (int*)(w + 2036516);   // 65
    // ---- zero-initialized region (one contiguous memset) ----
    int*   deg      = (int*)(w + 2036584);   // 20,000
    float* sums     = w + 2056584;           // 32,768
    // end: 2,089,352 units ≈ 8.4 MB

    hipMemsetAsync(w + 2036584, 0, (size_t)(20000 + 32768) * 4, stream);

    k_prep   <<<HB + CB + AB + NN / 4, 256, 0, stream>>>(ei, deg, W2, W2bfT, as2, ad2,
                                                         a2ps, a2pd, x, W1, as1, ad1,
                                                         h1bf, al_s1, al_d1);
    k_scan   <<<1, 1024, 0, stream>>>(deg, batch, rowstart, cursor, gstart);
    k_scatter<<<HB, 256, 0, stream>>>(ei, cursor, csr_src);
    k_l1     <<<NN / 4, 256, 0, stream>>>(rowstart, csr_src, al_s1, al_d1, h1bf, b1,
                                          a2ps, a2pd, o1bf, al_s2, al_d2);
    k_l2gemm <<<NN / 16, 512, 0, stream>>>(rowstart, csr_src, al_s2, al_d2, o1bf,
                                           W2bfT, b2, batch, sums);
    k_final  <<<NG * 8, 64, 0, stream>>>(sums, gstart, Wo, bo, out);
}